// Round 2
// baseline (450.042 us; speedup 1.0000x reference)
//
#include <hip/hip_runtime.h>

// SpatialMemoryGrid, two-kernel split:
//   K1 smg_pack : out[cell] = [ state(cell) , conf(cell)*0.95 , temp(cell) ]
//                 pure pack/copy, ALL writes aligned float4.
//   K2 smg_fixup: rewrite the B*NOBJ = 64 target cells with the blend /
//                 conf-update / temporal-add, computed from pristine inputs.
//                 Runs after K1 on the same stream; (b,o) -> cell is
//                 collision-free (o is a grid axis), so overwrite is exact.
//
// Geometry: B=4, GH=64, GW=64, N=16, F=256; cells = 262144.
// Out cell stride = 258 floats = 1032 B (only 8B-aligned), but a PAIR of
// cells = 516 floats = 129 float4s, 16B-aligned. K1 enumerates output
// float4s flat: tid -> (pair = tid/129, j = tid%129).
//   j in [0,64)  : state float4 j of even cell (aligned float4 load)
//   j == 64      : { confE*0.95, tempE, stateO[0], stateO[1] }
//   j in [65,128): floats 4k+2..4k+5 of odd cell's state (two float2 loads)
//   j == 128     : { stateO[254], stateO[255], confO*0.95, tempO }

#define GH 64
#define GW 64
#define NOBJ 16
#define FEAT 256
#define DECAYF 0.95f

__global__ __launch_bounds__(256) void smg_pack(
    const float4* __restrict__ state4,   // grid_state as float4 [cells*64]
    const float2* __restrict__ state2,   // grid_state as float2 [cells*128]
    const float*  __restrict__ conf,     // [cells]
    const float*  __restrict__ temp,     // [cells]
    float4*       __restrict__ out4,     // out as float4 [pairs*129]
    int total4)
{
    const int tid = blockIdx.x * 256 + threadIdx.x;
    if (tid >= total4) return;
    const unsigned q = (unsigned)tid / 129u;       // cell pair
    const unsigned j = (unsigned)tid - q * 129u;   // float4 slot within pair
    const unsigned cellE = 2u * q;
    const unsigned cellO = cellE + 1u;

    float4 v;
    if (j < 64u) {
        v = state4[(size_t)cellE * 64u + j];
    } else if (j == 64u) {
        const float2 s = state2[(size_t)cellO * 128u];
        v.x = conf[cellE] * DECAYF;
        v.y = temp[cellE];
        v.z = s.x;
        v.w = s.y;
    } else if (j < 128u) {
        const unsigned k = j - 65u;
        const size_t base = (size_t)cellO * 128u;
        const float2 a = state2[base + 2u * k + 1u];
        const float2 b = state2[base + 2u * k + 2u];
        v.x = a.x; v.y = a.y; v.z = b.x; v.w = b.y;
    } else {  // j == 128
        const float2 s = state2[(size_t)cellO * 128u + 127u];
        v.x = s.x;
        v.y = s.y;
        v.z = conf[cellO] * DECAYF;
        v.w = temp[cellO];
    }
    out4[tid] = v;
}

__global__ __launch_bounds__(64) void smg_fixup(
    const float*  __restrict__ state,   // [cells*FEAT]
    const float*  __restrict__ conf,    // [cells]
    const float*  __restrict__ temp,    // [cells]
    const float*  __restrict__ objf,    // [B*NOBJ*FEAT]
    const float*  __restrict__ pos,     // [B*NOBJ*2]
    const float*  __restrict__ occl,    // [B*NOBJ]
    float*        __restrict__ out)     // [cells*258]
{
    const int bo = blockIdx.x;                 // one block per (b, o)
    const int b  = bo >> 4;
    const int o  = bo & (NOBJ - 1);

    const float px = pos[bo * 2 + 0];
    const float py = pos[bo * 2 + 1];
    const int gwt = (int)fminf(fmaxf(px * (float)(GW - 1), 0.0f), 63.0f);
    const int ght = (int)fminf(fmaxf(py * (float)(GH - 1), 0.0f), 63.0f);
    const int cell = ((b * GH + ght) * GW + gwt) * NOBJ + o;

    const bool  vis   = occl[bo] < 0.5f;
    const float alpha = vis ? 0.8f : 0.3f;
    const float beta  = 1.0f - alpha;

    const int i = threadIdx.x;                 // float4 slot 0..63 of state row
    const float4 w = ((const float4*)objf)[bo * 64 + i];
    const float4 s = ((const float4*)state)[(size_t)cell * 64 + i];
    float4 r;
    r.x = alpha * w.x + beta * s.x;
    r.y = alpha * w.y + beta * s.y;
    r.z = alpha * w.z + beta * s.z;
    r.w = alpha * w.w + beta * s.w;

    float* ob = out + (size_t)cell * (FEAT + 2) + 4 * i;   // 8B-aligned
    ((float2*)ob)[0] = make_float2(r.x, r.y);
    ((float2*)ob)[1] = make_float2(r.z, r.w);

    if (i == 0) {
        float c = conf[cell];
        c = vis ? fminf(1.0f, c * 0.9f + 0.5f) : c * DECAYF;
        const float t = temp[cell] + (vis ? 1.0f : 0.5f);
        ((float2*)(out + (size_t)cell * (FEAT + 2) + FEAT))[0] =
            make_float2(c * DECAYF, t);
    }
}

extern "C" void kernel_launch(void* const* d_in, const int* in_sizes, int n_in,
                              void* d_out, int out_size, void* d_ws, size_t ws_size,
                              hipStream_t stream) {
    const float* grid_state = (const float*)d_in[0];
    const float* grid_conf  = (const float*)d_in[1];
    const float* grid_temp  = (const float*)d_in[2];
    const float* obj_feat   = (const float*)d_in[3];
    const float* positions  = (const float*)d_in[4];
    const float* occl       = (const float*)d_in[5];
    float* out = (float*)d_out;

    const int B      = in_sizes[5] / NOBJ;            // 4
    const int cells  = B * GH * GW * NOBJ;            // 262144
    const int total4 = (cells / 2) * 129;             // 16,908,288 output float4s
    const int blocks = (total4 + 255) / 256;          // 66048

    smg_pack<<<blocks, 256, 0, stream>>>(
        (const float4*)grid_state, (const float2*)grid_state,
        grid_conf, grid_temp, (float4*)out, total4);

    smg_fixup<<<B * NOBJ, 64, 0, stream>>>(
        grid_state, grid_conf, grid_temp, obj_feat, positions, occl, out);
}